// Round 1
// baseline (1079.841 us; speedup 1.0000x reference)
//
#include <hip/hip_runtime.h>
#include <hip/hip_bf16.h>
#include <type_traits>
#include <utility>

// ---------------------------------------------------------------------------
// C = tril(A @ B), N=8192, A,B lower-triangular fp32.
// Strategy: convert A->bf16 (same layout), B->bf16 transposed (Bt[n][k]),
// then bf16 MFMA GEMM over lower-triangular 128x128 tiles only, with
// K-range [bj*128, (bi+1)*128) (triangular structure => 1/5.7 of full work).
// Upper tiles of C are zero-filled (d_out is poisoned 0xAA each launch).
// ---------------------------------------------------------------------------

static constexpr int MATN = 8192;

typedef __attribute__((ext_vector_type(8))) short  s8v;
typedef __attribute__((ext_vector_type(8))) __bf16 b8v;
typedef __attribute__((ext_vector_type(4))) float  f4v;

// --- pick whichever vector element type the gfx950 bf16 MFMA builtin wants ---
template <typename V, typename = void>
struct mfma_ok : std::false_type {};
template <typename V>
struct mfma_ok<V, std::void_t<decltype(__builtin_amdgcn_mfma_f32_16x16x32_bf16(
    std::declval<V>(), std::declval<V>(), std::declval<f4v>(), 0, 0, 0))>>
    : std::true_type {};
using abv = std::conditional_t<mfma_ok<b8v>::value, b8v, s8v>;

// fp32 -> bf16 round-to-nearest-even (bit pattern as short)
__device__ __forceinline__ short f2bf(float f) {
  unsigned u = __builtin_bit_cast(unsigned, f);
  unsigned r = (u + 0x7fffu + ((u >> 16) & 1u)) >> 16;
  return (short)r;
}

// async global->LDS 16B per lane; LDS dest = wave-uniform base + lane*16
__device__ __forceinline__ void async16(void* lds, const void* g) {
  __builtin_amdgcn_global_load_lds(
      (const __attribute__((address_space(1))) unsigned int*)g,
      (__attribute__((address_space(3))) unsigned int*)lds, 16, 0, 0);
}

// ---------------------------------------------------------------------------
// Kernel 1: A (fp32, MxK) -> Abf (bf16, MxK). Chunks strictly above the
// diagonal are written as zeros without loading.
// ---------------------------------------------------------------------------
__global__ __launch_bounds__(256) void convert_A_k(const float* __restrict__ A,
                                                   short* __restrict__ Abf) {
  int gid  = blockIdx.x * 256 + threadIdx.x;
  int base = gid * 8;                       // 8 elements per thread
  int row  = base >> 13;                    // / 8192
  int col  = base & 8191;
  s8v o = {};
  if (col <= row) {                         // chunk intersects lower triangle
    f4v v0 = *(const f4v*)&A[base];
    f4v v1 = *(const f4v*)&A[base + 4];
#pragma unroll
    for (int i = 0; i < 4; i++) { o[i] = f2bf(v0[i]); o[4 + i] = f2bf(v1[i]); }
  }
  *(s8v*)&Abf[base] = o;
}

// ---------------------------------------------------------------------------
// Kernel 2: B (fp32, KxN) -> Bt (bf16, NxK), LDS tile transpose 64x64.
// Bt[n][k] = B[k][n]; tile all-zero iff k0+63 < n0.
// ---------------------------------------------------------------------------
__global__ __launch_bounds__(256) void transpose_B_k(const float* __restrict__ B,
                                                     short* __restrict__ Bt) {
  __shared__ __align__(16) short T[64][72];  // pad: row stride 144B (16B-aligned)
  int k0 = blockIdx.x * 64, n0 = blockIdx.y * 64;
  int tid = threadIdx.x;
  if (k0 + 63 < n0) {                        // entirely zero tile of Bt
    s8v z = {};
#pragma unroll
    for (int t = 0; t < 2; t++) {
      int c = t * 256 + tid;                 // 512 chunks of 8 bf16
      int n = c >> 3, kc = (c & 7) * 8;
      *(s8v*)&Bt[(size_t)(n0 + n) * MATN + k0 + kc] = z;
    }
    return;
  }
#pragma unroll
  for (int t = 0; t < 4; t++) {              // 1024 float4 chunks
    int c = t * 256 + tid;
    int k = c >> 4, nc = (c & 15) * 4;
    f4v v = *(const f4v*)&B[(size_t)(k0 + k) * MATN + n0 + nc];
#pragma unroll
    for (int i = 0; i < 4; i++) T[nc + i][k] = f2bf(v[i]);
  }
  __syncthreads();
#pragma unroll
  for (int t = 0; t < 2; t++) {
    int c = t * 256 + tid;
    int n = c >> 3, kc = (c & 7) * 8;
    s8v o = *(const s8v*)&T[n][kc];
    *(s8v*)&Bt[(size_t)(n0 + n) * MATN + k0 + kc] = o;
  }
}

// ---------------------------------------------------------------------------
// Kernel 3: the triangular bf16 MFMA GEMM. Grid 64x64 of 128x128 tiles.
// bi<bj: zero-fill. bi>=bj: K in [bj*128,(bi+1)*128). m97 structure:
// BK=32, 4 waves, each 64x64 = 4x4 MFMA 16x16x32, global_load_lds staging.
// ---------------------------------------------------------------------------
__global__ __launch_bounds__(256) void gemm_tril(const short* __restrict__ Abf,
                                                 const short* __restrict__ Btb,
                                                 float* __restrict__ C) {
  int bj = blockIdx.x, bi = blockIdx.y;
  int tid = threadIdx.x;
  if (bi < bj) {                             // zero tile
    f4v z = {};
    size_t base = (size_t)bi * 128 * MATN + (size_t)bj * 128;
#pragma unroll
    for (int t = 0; t < 16; t++) {           // 4096 float4 chunks
      int c = t * 256 + tid;
      int r = c >> 5, cc = (c & 31) * 4;
      *(f4v*)&C[base + (size_t)r * MATN + cc] = z;
    }
    return;
  }

  __shared__ __align__(16) short As[128 * 32];
  __shared__ __align__(16) short Bs[128 * 32];

  int wave = tid >> 6, lane = tid & 63;
  int quad = lane >> 4, ln = lane & 15;
  int wm = wave >> 1, wn = wave & 1;

  int row0 = bi * 128, col0 = bj * 128;
  f4v acc[4][4] = {};

  // staging: 512 chunks of 16B per 128x32 tile; 2 issues x 256 threads
  int r0 = tid >> 2, c0 = (tid & 3) * 8;     // issue 0: rows 0..63
  int r1 = 64 + r0;                          // issue 1: rows 64..127
  char* lA0 = (char*)As + wave * 1024;
  char* lA1 = (char*)As + 4096 + wave * 1024;
  char* lB0 = (char*)Bs + wave * 1024;
  char* lB1 = (char*)Bs + 4096 + wave * 1024;

  int kend = (bi + 1) * 128;
  for (int kt = col0; kt < kend; kt += 32) {
    __syncthreads();                         // prev iter done reading LDS
    async16(lA0, &Abf[(size_t)(row0 + r0) * MATN + kt + c0]);
    async16(lA1, &Abf[(size_t)(row0 + r1) * MATN + kt + c0]);
    async16(lB0, &Btb[(size_t)(col0 + r0) * MATN + kt + c0]);
    async16(lB1, &Btb[(size_t)(col0 + r1) * MATN + kt + c0]);
    __syncthreads();                         // drains vmcnt before barrier

    abv a[4], b[4];
#pragma unroll
    for (int t = 0; t < 4; t++) {
      a[t] = *(const abv*)&As[(wm * 64 + t * 16 + ln) * 32 + quad * 8];
      b[t] = *(const abv*)&Bs[(wn * 64 + t * 16 + ln) * 32 + quad * 8];
    }
#pragma unroll
    for (int tm = 0; tm < 4; tm++)
#pragma unroll
      for (int tn = 0; tn < 4; tn++)
        acc[tm][tn] = __builtin_amdgcn_mfma_f32_16x16x32_bf16(
            a[tm], b[tn], acc[tm][tn], 0, 0, 0);
  }

  // epilogue: C/D layout col=lane&15, row=quad*4+reg; tril mask (diag tiles)
#pragma unroll
  for (int tm = 0; tm < 4; tm++) {
    int grb = row0 + wm * 64 + tm * 16 + quad * 4;
#pragma unroll
    for (int tn = 0; tn < 4; tn++) {
      int gc = col0 + wn * 64 + tn * 16 + ln;
#pragma unroll
      for (int r = 0; r < 4; r++) {
        int gr = grb + r;
        C[(size_t)gr * MATN + gc] = (gr >= gc) ? acc[tm][tn][r] : 0.0f;
      }
    }
  }
}

// ---------------------------------------------------------------------------
// Fallback (only if ws too small for the two bf16 matrices): correct fp32
// LDS-tiled GEMM, 64x64 tiles, triangular K-range + tril mask.
// ---------------------------------------------------------------------------
__global__ __launch_bounds__(256) void gemm_tril_f32(const float* __restrict__ A,
                                                     const float* __restrict__ B,
                                                     float* __restrict__ C) {
  int bj = blockIdx.x, bi = blockIdx.y;      // 128x128 grid of 64x64 tiles
  int tid = threadIdx.x;
  int row0 = bi * 64, col0 = bj * 64;
  if (bi < bj) {
    f4v z = {};
#pragma unroll
    for (int t = 0; t < 4; t++) {
      int c = t * 256 + tid;
      int r = c >> 4, cc = (c & 15) * 4;
      *(f4v*)&C[(size_t)(row0 + r) * MATN + col0 + cc] = z;
    }
    return;
  }
  __shared__ float As[64][17];
  __shared__ float Bs[16][65];
  int tx = tid & 15, ty = tid >> 4;
  float acc[4][4] = {};
  int kendf = (bi + 1) * 64;
  for (int kt = col0; kt < kendf; kt += 16) {
    __syncthreads();
#pragma unroll
    for (int t = 0; t < 4; t++) {
      int c = t * 256 + tid;
      int r = c >> 4, k = c & 15;
      As[r][k] = A[(size_t)(row0 + r) * MATN + kt + k];
    }
#pragma unroll
    for (int t = 0; t < 4; t++) {
      int c = t * 256 + tid;
      int k = c >> 6, n = c & 63;
      Bs[k][n] = B[(size_t)(kt + k) * MATN + col0 + n];
    }
    __syncthreads();
#pragma unroll
    for (int k = 0; k < 16; k++) {
      float av[4], bv[4];
#pragma unroll
      for (int i = 0; i < 4; i++) av[i] = As[ty * 4 + i][k];
#pragma unroll
      for (int j = 0; j < 4; j++) bv[j] = Bs[k][tx * 4 + j];
#pragma unroll
      for (int i = 0; i < 4; i++)
#pragma unroll
        for (int j = 0; j < 4; j++) acc[i][j] += av[i] * bv[j];
    }
  }
#pragma unroll
  for (int i = 0; i < 4; i++)
#pragma unroll
    for (int j = 0; j < 4; j++) {
      int gr = row0 + ty * 4 + i, gc = col0 + tx * 4 + j;
      C[(size_t)gr * MATN + gc] = (gr >= gc) ? acc[i][j] : 0.0f;
    }
}

// ---------------------------------------------------------------------------
extern "C" void kernel_launch(void* const* d_in, const int* in_sizes, int n_in,
                              void* d_out, int out_size, void* d_ws, size_t ws_size,
                              hipStream_t stream) {
  const float* A = (const float*)d_in[0];
  const float* B = (const float*)d_in[1];
  float* C = (float*)d_out;

  const size_t need = 2ull * MATN * MATN * sizeof(short);  // 256 MiB
  if (ws_size >= need) {
    short* Abf = (short*)d_ws;
    short* Btb = Abf + (size_t)MATN * MATN;
    convert_A_k<<<(MATN * (size_t)MATN) / 8 / 256, 256, 0, stream>>>(A, Abf);
    transpose_B_k<<<dim3(MATN / 64, MATN / 64), 256, 0, stream>>>(B, Btb);
    gemm_tril<<<dim3(MATN / 128, MATN / 128), 256, 0, stream>>>(Abf, Btb, C);
  } else {
    gemm_tril_f32<<<dim3(MATN / 64, MATN / 64), 256, 0, stream>>>(A, B, C);
  }
}

// Round 2
// 979.684 us; speedup vs baseline: 1.1022x; 1.1022x over previous
//
#include <hip/hip_runtime.h>
#include <hip/hip_bf16.h>
#include <type_traits>
#include <utility>

// ---------------------------------------------------------------------------
// C = tril(A @ B), N=8192, A,B lower-triangular fp32.
// convert A->bf16 (same layout), B->bf16 transposed (Bt[n][k]), then bf16
// MFMA GEMM over lower-triangular 128x128 tiles with K in [bj*128,(bi+1)*128).
// GEMM blocks ordered longest-diagonal-first to kill the dispatch tail.
// ---------------------------------------------------------------------------

static constexpr int MATN = 8192;

typedef __attribute__((ext_vector_type(8))) short  s8v;
typedef __attribute__((ext_vector_type(4))) short  s4h;
typedef __attribute__((ext_vector_type(8))) __bf16 b8v;
typedef __attribute__((ext_vector_type(4))) float  f4v;

template <typename V, typename = void>
struct mfma_ok : std::false_type {};
template <typename V>
struct mfma_ok<V, std::void_t<decltype(__builtin_amdgcn_mfma_f32_16x16x32_bf16(
    std::declval<V>(), std::declval<V>(), std::declval<f4v>(), 0, 0, 0))>>
    : std::true_type {};
using abv = std::conditional_t<mfma_ok<b8v>::value, b8v, s8v>;

__device__ __forceinline__ short f2bf(float f) {
  unsigned u = __builtin_bit_cast(unsigned, f);
  unsigned r = (u + 0x7fffu + ((u >> 16) & 1u)) >> 16;
  return (short)r;
}

__device__ __forceinline__ void async16(void* lds, const void* g) {
  __builtin_amdgcn_global_load_lds(
      (const __attribute__((address_space(1))) unsigned int*)g,
      (__attribute__((address_space(3))) unsigned int*)lds, 16, 0, 0);
}

// id -> triangular index: largest k with k(k+1)/2 <= id
__device__ __forceinline__ int tri_decode(int id) {
  int k = (int)((sqrtf(8.0f * (float)id + 1.0f) - 1.0f) * 0.5f);
  while ((k + 1) * (k + 2) / 2 <= id) k++;
  while (k * (k + 1) / 2 > id) k--;
  return k;
}

// ---------------------------------------------------------------------------
// Kernel 1: A (fp32) -> Abf (bf16), same layout. Upper chunks: write zeros,
// skip the load.
// ---------------------------------------------------------------------------
__global__ __launch_bounds__(256) void convert_A_k(const float* __restrict__ A,
                                                   short* __restrict__ Abf) {
  int gid  = blockIdx.x * 256 + threadIdx.x;
  int base = gid * 8;
  int row  = base >> 13;
  int col  = base & 8191;
  s8v o = {};
  if (col <= row) {
    f4v v0 = *(const f4v*)&A[base];
    f4v v1 = *(const f4v*)&A[base + 4];
#pragma unroll
    for (int i = 0; i < 4; i++) { o[i] = f2bf(v0[i]); o[4 + i] = f2bf(v1[i]); }
  }
  *(s8v*)&Abf[base] = o;
}

// ---------------------------------------------------------------------------
// Kernel 2: B (fp32, KxN) -> Bt (bf16, NxK). 64x64 tile.
// LDS stored ROW-major (k-major) as loaded: packed ds_write_b64, bank-uniform.
// Transposed read = scalar b16 with XOR column swizzle n' = n ^ 8*(k>>3)
// -> 2 lanes/bank (free). Global loads 256B-segment, stores 128B-segment.
// ---------------------------------------------------------------------------
__global__ __launch_bounds__(256) void transpose_B_k(const float* __restrict__ B,
                                                     short* __restrict__ Bt) {
  __shared__ __align__(16) short T[64 * 68];   // 68-short rows: b64-aligned
  int k0 = blockIdx.x * 64, n0 = blockIdx.y * 64;
  int tid = threadIdx.x;
  if (k0 + 63 < n0) {                          // tile of Bt entirely zero
    s8v z = {};
#pragma unroll
    for (int t = 0; t < 2; t++) {
      int c = t * 256 + tid;
      int n = c >> 3, kg = c & 7;
      *(s8v*)&Bt[(size_t)(n0 + n) * MATN + k0 + kg * 8] = z;
    }
    return;
  }
#pragma unroll
  for (int t = 0; t < 4; t++) {                // 1024 chunks of 4 floats
    int c = t * 256 + tid;
    int k = c >> 4, cn = c & 15;
    s4h o = {};
    if (n0 + cn * 4 <= k0 + k) {               // else structurally zero
      f4v v = *(const f4v*)&B[(size_t)(k0 + k) * MATN + n0 + cn * 4];
#pragma unroll
      for (int i = 0; i < 4; i++) o[i] = f2bf(v[i]);
    }
    int cs = cn ^ (2 * (k >> 3));              // column-group swizzle
    *(s4h*)&T[k * 68 + cs * 4] = o;            // ds_write_b64, conflict-free
  }
  __syncthreads();
#pragma unroll
  for (int t = 0; t < 2; t++) {                // 512 output chunks of 8 k
    int c = t * 256 + tid;
    int n = c >> 3, kg = c & 7;
    int nn = n ^ (kg * 8);                     // unswizzle
    s8v o;
#pragma unroll
    for (int i = 0; i < 8; i++) o[i] = T[(kg * 8 + i) * 68 + nn];
    *(s8v*)&Bt[(size_t)(n0 + n) * MATN + k0 + kg * 8] = o;
  }
}

// ---------------------------------------------------------------------------
// Kernel 3: triangular bf16 MFMA GEMM, 1D grid of 4096 blocks.
// id < 2080: lower tiles, longest diagonal first (d = bi-bj descending).
// id >= 2080: upper tiles, zero-fill only.
// ---------------------------------------------------------------------------
__global__ __launch_bounds__(256) void gemm_tril(const short* __restrict__ Abf,
                                                 const short* __restrict__ Btb,
                                                 float* __restrict__ C) {
  int id = blockIdx.x;
  int tid = threadIdx.x;
  int bi, bj;
  if (id >= 2080) {                            // upper: zero tile
    int u = id - 2080;
    int r = tri_decode(u);
    bi = u - r * (r + 1) / 2;                  // bi <= r
    bj = r + 1;                                // bi < bj
    f4v z = {};
    size_t base = (size_t)bi * 128 * MATN + (size_t)bj * 128;
#pragma unroll
    for (int t = 0; t < 16; t++) {
      int c = t * 256 + tid;
      int r2 = c >> 5, cc = (c & 31) * 4;
      *(f4v*)&C[base + (size_t)r2 * MATN + cc] = z;
    }
    return;
  }
  {                                            // lower: longest-first decode
    int k = tri_decode(id);                    // diag d = 63-k has k+1 tiles
    int idx = id - k * (k + 1) / 2;
    bj = idx;
    bi = idx + 63 - k;
  }

  __shared__ __align__(16) short As[128 * 32];
  __shared__ __align__(16) short Bs[128 * 32];

  int wave = tid >> 6, lane = tid & 63;
  int quad = lane >> 4, ln = lane & 15;
  int wm = wave >> 1, wn = wave & 1;

  int row0 = bi * 128, col0 = bj * 128;
  f4v acc[4][4] = {};

  int r0 = tid >> 2, c0 = (tid & 3) * 8;
  int r1 = 64 + r0;
  char* lA0 = (char*)As + wave * 1024;
  char* lA1 = (char*)As + 4096 + wave * 1024;
  char* lB0 = (char*)Bs + wave * 1024;
  char* lB1 = (char*)Bs + 4096 + wave * 1024;

  int kend = (bi + 1) * 128;
  for (int kt = col0; kt < kend; kt += 32) {
    __syncthreads();
    async16(lA0, &Abf[(size_t)(row0 + r0) * MATN + kt + c0]);
    async16(lA1, &Abf[(size_t)(row0 + r1) * MATN + kt + c0]);
    async16(lB0, &Btb[(size_t)(col0 + r0) * MATN + kt + c0]);
    async16(lB1, &Btb[(size_t)(col0 + r1) * MATN + kt + c0]);
    __syncthreads();

    abv a[4], b[4];
#pragma unroll
    for (int t = 0; t < 4; t++) {
      a[t] = *(const abv*)&As[(wm * 64 + t * 16 + ln) * 32 + quad * 8];
      b[t] = *(const abv*)&Bs[(wn * 64 + t * 16 + ln) * 32 + quad * 8];
    }
#pragma unroll
    for (int tm = 0; tm < 4; tm++)
#pragma unroll
      for (int tn = 0; tn < 4; tn++)
        acc[tm][tn] = __builtin_amdgcn_mfma_f32_16x16x32_bf16(
            a[tm], b[tn], acc[tm][tn], 0, 0, 0);
  }

  // epilogue: C/D layout col=lane&15, row=quad*4+reg
  bool diag = (bi == bj);
#pragma unroll
  for (int tm = 0; tm < 4; tm++) {
    int grb = row0 + wm * 64 + tm * 16 + quad * 4;
#pragma unroll
    for (int tn = 0; tn < 4; tn++) {
      int gc = col0 + wn * 64 + tn * 16 + ln;
#pragma unroll
      for (int r = 0; r < 4; r++) {
        int gr = grb + r;
        float v = acc[tm][tn][r];
        if (diag && gr < gc) v = 0.0f;
        C[(size_t)gr * MATN + gc] = v;
      }
    }
  }
}

// ---------------------------------------------------------------------------
// Fallback: correct fp32 LDS-tiled GEMM (only if ws too small).
// ---------------------------------------------------------------------------
__global__ __launch_bounds__(256) void gemm_tril_f32(const float* __restrict__ A,
                                                     const float* __restrict__ B,
                                                     float* __restrict__ C) {
  int bj = blockIdx.x, bi = blockIdx.y;
  int tid = threadIdx.x;
  int row0 = bi * 64, col0 = bj * 64;
  if (bi < bj) {
    f4v z = {};
#pragma unroll
    for (int t = 0; t < 4; t++) {
      int c = t * 256 + tid;
      int r = c >> 4, cc = (c & 15) * 4;
      *(f4v*)&C[(size_t)(row0 + r) * MATN + col0 + cc] = z;
    }
    return;
  }
  __shared__ float As[64][17];
  __shared__ float Bs[16][65];
  int tx = tid & 15, ty = tid >> 4;
  float acc[4][4] = {};
  int kendf = (bi + 1) * 64;
  for (int kt = col0; kt < kendf; kt += 16) {
    __syncthreads();
#pragma unroll
    for (int t = 0; t < 4; t++) {
      int c = t * 256 + tid;
      int r = c >> 4, k = c & 15;
      As[r][k] = A[(size_t)(row0 + r) * MATN + kt + k];
    }
#pragma unroll
    for (int t = 0; t < 4; t++) {
      int c = t * 256 + tid;
      int k = c >> 6, n = c & 63;
      Bs[k][n] = B[(size_t)(kt + k) * MATN + col0 + n];
    }
    __syncthreads();
#pragma unroll
    for (int k = 0; k < 16; k++) {
      float av[4], bv[4];
#pragma unroll
      for (int i = 0; i < 4; i++) av[i] = As[ty * 4 + i][k];
#pragma unroll
      for (int j = 0; j < 4; j++) bv[j] = Bs[k][tx * 4 + j];
#pragma unroll
      for (int i = 0; i < 4; i++)
#pragma unroll
        for (int j = 0; j < 4; j++) acc[i][j] += av[i] * bv[j];
    }
  }
#pragma unroll
  for (int i = 0; i < 4; i++)
#pragma unroll
    for (int j = 0; j < 4; j++) {
      int gr = row0 + ty * 4 + i, gc = col0 + tx * 4 + j;
      C[(size_t)gr * MATN + gc] = (gr >= gc) ? acc[i][j] : 0.0f;
    }
}

// ---------------------------------------------------------------------------
extern "C" void kernel_launch(void* const* d_in, const int* in_sizes, int n_in,
                              void* d_out, int out_size, void* d_ws, size_t ws_size,
                              hipStream_t stream) {
  const float* A = (const float*)d_in[0];
  const float* B = (const float*)d_in[1];
  float* C = (float*)d_out;

  const size_t need = 2ull * MATN * MATN * sizeof(short);  // 256 MiB
  if (ws_size >= need) {
    short* Abf = (short*)d_ws;
    short* Btb = Abf + (size_t)MATN * MATN;
    convert_A_k<<<(MATN * (size_t)MATN) / 8 / 256, 256, 0, stream>>>(A, Abf);
    transpose_B_k<<<dim3(MATN / 64, MATN / 64), 256, 0, stream>>>(B, Btb);
    gemm_tril<<<4096, 256, 0, stream>>>(Abf, Btb, C);
  } else {
    gemm_tril_f32<<<dim3(MATN / 64, MATN / 64), 256, 0, stream>>>(A, B, C);
  }
}

// Round 3
// 900.678 us; speedup vs baseline: 1.1989x; 1.0877x over previous
//
#include <hip/hip_runtime.h>
#include <hip/hip_bf16.h>
#include <type_traits>
#include <utility>

// ---------------------------------------------------------------------------
// C = tril(A @ B), N=8192, A,B lower-triangular fp32.
// convert A->bf16, B->bf16 transposed, then bf16 MFMA GEMM over lower
// 128x128 tiles, K in [bj*128,(bi+1)*128). Blocks grouped into 8x8-tile
// supertiles ordered far-from-diagonal first: long-K tiles start first AND
// concurrent blocks share A row-bands / B panels in L3 (fetch ~3x lower).
// ---------------------------------------------------------------------------

static constexpr int MATN = 8192;

typedef __attribute__((ext_vector_type(8))) short  s8v;
typedef __attribute__((ext_vector_type(4))) short  s4h;
typedef __attribute__((ext_vector_type(8))) __bf16 b8v;
typedef __attribute__((ext_vector_type(4))) float  f4v;

template <typename V, typename = void>
struct mfma_ok : std::false_type {};
template <typename V>
struct mfma_ok<V, std::void_t<decltype(__builtin_amdgcn_mfma_f32_16x16x32_bf16(
    std::declval<V>(), std::declval<V>(), std::declval<f4v>(), 0, 0, 0))>>
    : std::true_type {};
using abv = std::conditional_t<mfma_ok<b8v>::value, b8v, s8v>;

__device__ __forceinline__ short f2bf(float f) {
  unsigned u = __builtin_bit_cast(unsigned, f);
  unsigned r = (u + 0x7fffu + ((u >> 16) & 1u)) >> 16;
  return (short)r;
}

__device__ __forceinline__ void async16(void* lds, const void* g) {
  __builtin_amdgcn_global_load_lds(
      (const __attribute__((address_space(1))) unsigned int*)g,
      (__attribute__((address_space(3))) unsigned int*)lds, 16, 0, 0);
}

// largest k with k(k+1)/2 <= id
__device__ __forceinline__ int tri_decode(int id) {
  int k = (int)((sqrtf(8.0f * (float)id + 1.0f) - 1.0f) * 0.5f);
  while ((k + 1) * (k + 2) / 2 <= id) k++;
  while (k * (k + 1) / 2 > id) k--;
  return k;
}

// ---------------------------------------------------------------------------
// Kernel 1: A (fp32) -> Abf (bf16), same layout; upper chunks write zeros
// without loading (A is tril, but Abf upper must be genuine zeros since the
// GEMM stages full 128-row x K bands).
// ---------------------------------------------------------------------------
__global__ __launch_bounds__(256) void convert_A_k(const float* __restrict__ A,
                                                   short* __restrict__ Abf) {
  int gid  = blockIdx.x * 256 + threadIdx.x;
  int base = gid * 8;
  int row  = base >> 13;
  int col  = base & 8191;
  s8v o = {};
  if (col <= row) {
    f4v v0 = *(const f4v*)&A[base];
    f4v v1 = *(const f4v*)&A[base + 4];
#pragma unroll
    for (int i = 0; i < 4; i++) { o[i] = f2bf(v0[i]); o[4 + i] = f2bf(v1[i]); }
  }
  *(s8v*)&Abf[base] = o;
}

// ---------------------------------------------------------------------------
// Kernel 2: B (fp32, KxN) -> Bt (bf16, NxK). 64x64 tile; LDS row-major with
// packed b64 writes (bank-minimum), transposed b16 reads with XOR swizzle
// (2 lanes/bank = free).
// ---------------------------------------------------------------------------
__global__ __launch_bounds__(256) void transpose_B_k(const float* __restrict__ B,
                                                     short* __restrict__ Bt) {
  __shared__ __align__(16) short T[64 * 68];
  int k0 = blockIdx.x * 64, n0 = blockIdx.y * 64;
  int tid = threadIdx.x;
  if (k0 + 63 < n0) {                          // Bt tile entirely zero
    s8v z = {};
#pragma unroll
    for (int t = 0; t < 2; t++) {
      int c = t * 256 + tid;
      int n = c >> 3, kg = c & 7;
      *(s8v*)&Bt[(size_t)(n0 + n) * MATN + k0 + kg * 8] = z;
    }
    return;
  }
#pragma unroll
  for (int t = 0; t < 4; t++) {
    int c = t * 256 + tid;
    int k = c >> 4, cn = c & 15;
    s4h o = {};
    if (n0 + cn * 4 <= k0 + k) {               // else structurally zero
      f4v v = *(const f4v*)&B[(size_t)(k0 + k) * MATN + n0 + cn * 4];
#pragma unroll
      for (int i = 0; i < 4; i++) o[i] = f2bf(v[i]);
    }
    int cs = cn ^ (2 * (k >> 3));
    *(s4h*)&T[k * 68 + cs * 4] = o;
  }
  __syncthreads();
#pragma unroll
  for (int t = 0; t < 2; t++) {
    int c = t * 256 + tid;
    int n = c >> 3, kg = c & 7;
    int nn = n ^ (kg * 8);
    s8v o;
#pragma unroll
    for (int i = 0; i < 8; i++) o[i] = T[(kg * 8 + i) * 68 + nn];
    *(s8v*)&Bt[(size_t)(n0 + n) * MATN + k0 + kg * 8] = o;
  }
}

// ---------------------------------------------------------------------------
// Kernel 3: triangular bf16 MFMA GEMM. Grid 4096.
// ids [0,2304): 36 lower supertiles (8x8 tiles), D=I-J descending; bi desc
//               row-major inside. Diagonal supertiles contain some upper
//               tiles -> zero path.
// ids [2304,4096): 28 upper supertiles -> zero-fill.
// ---------------------------------------------------------------------------
__global__ __launch_bounds__(256) void gemm_tril(const short* __restrict__ Abf,
                                                 const short* __restrict__ Btb,
                                                 float* __restrict__ C) {
  int id = blockIdx.x;
  int tid = threadIdx.x;
  int bi, bj;
  if (id < 2304) {                             // lower supertiles, D desc
    int s = id >> 6;
    int t = tri_decode(s);                     // t = 7 - D
    int J = s - t * (t + 1) / 2;
    int I = J + 7 - t;
    int li = 7 - ((id >> 3) & 7);              // long rows first
    int lj = id & 7;
    bi = I * 8 + li;
    bj = J * 8 + lj;
  } else {                                     // upper supertiles
    int q = id - 2304;
    int s = q >> 6;
    int r = tri_decode(s);
    int I = s - r * (r + 1) / 2;
    int J = r + 1;
    bi = I * 8 + ((q >> 3) & 7);
    bj = J * 8 + (q & 7);
  }

  if (bi < bj) {                               // zero tile
    f4v z = {};
    size_t base = (size_t)bi * 128 * MATN + (size_t)bj * 128;
#pragma unroll
    for (int t = 0; t < 16; t++) {
      int c = t * 256 + tid;
      int r2 = c >> 5, cc = (c & 31) * 4;
      *(f4v*)&C[base + (size_t)r2 * MATN + cc] = z;
    }
    return;
  }

  __shared__ __align__(16) short As[128 * 32];
  __shared__ __align__(16) short Bs[128 * 32];

  int wave = tid >> 6, lane = tid & 63;
  int quad = lane >> 4, ln = lane & 15;
  int wm = wave >> 1, wn = wave & 1;

  int row0 = bi * 128, col0 = bj * 128;
  f4v acc[4][4] = {};

  int r0 = tid >> 2, c0 = (tid & 3) * 8;
  int r1 = 64 + r0;
  char* lA0 = (char*)As + wave * 1024;
  char* lA1 = (char*)As + 4096 + wave * 1024;
  char* lB0 = (char*)Bs + wave * 1024;
  char* lB1 = (char*)Bs + 4096 + wave * 1024;

  int kend = (bi + 1) * 128;
  for (int kt = col0; kt < kend; kt += 32) {
    __syncthreads();
    async16(lA0, &Abf[(size_t)(row0 + r0) * MATN + kt + c0]);
    async16(lA1, &Abf[(size_t)(row0 + r1) * MATN + kt + c0]);
    async16(lB0, &Btb[(size_t)(col0 + r0) * MATN + kt + c0]);
    async16(lB1, &Btb[(size_t)(col0 + r1) * MATN + kt + c0]);
    __syncthreads();

    abv a[4], b[4];
#pragma unroll
    for (int t = 0; t < 4; t++) {
      a[t] = *(const abv*)&As[(wm * 64 + t * 16 + ln) * 32 + quad * 8];
      b[t] = *(const abv*)&Bs[(wn * 64 + t * 16 + ln) * 32 + quad * 8];
    }
#pragma unroll
    for (int tm = 0; tm < 4; tm++)
#pragma unroll
      for (int tn = 0; tn < 4; tn++)
        acc[tm][tn] = __builtin_amdgcn_mfma_f32_16x16x32_bf16(
            a[tm], b[tn], acc[tm][tn], 0, 0, 0);
  }

  // epilogue: C/D layout col=lane&15, row=quad*4+reg
  bool diag = (bi == bj);
#pragma unroll
  for (int tm = 0; tm < 4; tm++) {
    int grb = row0 + wm * 64 + tm * 16 + quad * 4;
#pragma unroll
    for (int tn = 0; tn < 4; tn++) {
      int gc = col0 + wn * 64 + tn * 16 + ln;
#pragma unroll
      for (int r = 0; r < 4; r++) {
        int gr = grb + r;
        float v = acc[tm][tn][r];
        if (diag && gr < gc) v = 0.0f;
        C[(size_t)gr * MATN + gc] = v;
      }
    }
  }
}

// ---------------------------------------------------------------------------
// Fallback: correct fp32 LDS-tiled GEMM (only if ws too small).
// ---------------------------------------------------------------------------
__global__ __launch_bounds__(256) void gemm_tril_f32(const float* __restrict__ A,
                                                     const float* __restrict__ B,
                                                     float* __restrict__ C) {
  int bj = blockIdx.x, bi = blockIdx.y;
  int tid = threadIdx.x;
  int row0 = bi * 64, col0 = bj * 64;
  if (bi < bj) {
    f4v z = {};
#pragma unroll
    for (int t = 0; t < 4; t++) {
      int c = t * 256 + tid;
      int r = c >> 4, cc = (c & 15) * 4;
      *(f4v*)&C[(size_t)(row0 + r) * MATN + col0 + cc] = z;
    }
    return;
  }
  __shared__ float As[64][17];
  __shared__ float Bs[16][65];
  int tx = tid & 15, ty = tid >> 4;
  float acc[4][4] = {};
  int kendf = (bi + 1) * 64;
  for (int kt = col0; kt < kendf; kt += 16) {
    __syncthreads();
#pragma unroll
    for (int t = 0; t < 4; t++) {
      int c = t * 256 + tid;
      int r = c >> 4, k = c & 15;
      As[r][k] = A[(size_t)(row0 + r) * MATN + kt + k];
    }
#pragma unroll
    for (int t = 0; t < 4; t++) {
      int c = t * 256 + tid;
      int k = c >> 6, n = c & 63;
      Bs[k][n] = B[(size_t)(kt + k) * MATN + col0 + n];
    }
    __syncthreads();
#pragma unroll
    for (int k = 0; k < 16; k++) {
      float av[4], bv[4];
#pragma unroll
      for (int i = 0; i < 4; i++) av[i] = As[ty * 4 + i][k];
#pragma unroll
      for (int j = 0; j < 4; j++) bv[j] = Bs[k][tx * 4 + j];
#pragma unroll
      for (int i = 0; i < 4; i++)
#pragma unroll
        for (int j = 0; j < 4; j++) acc[i][j] += av[i] * bv[j];
    }
  }
#pragma unroll
  for (int i = 0; i < 4; i++)
#pragma unroll
    for (int j = 0; j < 4; j++) {
      int gr = row0 + ty * 4 + i, gc = col0 + tx * 4 + j;
      C[(size_t)gr * MATN + gc] = (gr >= gc) ? acc[i][j] : 0.0f;
    }
}

// ---------------------------------------------------------------------------
extern "C" void kernel_launch(void* const* d_in, const int* in_sizes, int n_in,
                              void* d_out, int out_size, void* d_ws, size_t ws_size,
                              hipStream_t stream) {
  const float* A = (const float*)d_in[0];
  const float* B = (const float*)d_in[1];
  float* C = (float*)d_out;

  const size_t need = 2ull * MATN * MATN * sizeof(short);  // 256 MiB
  if (ws_size >= need) {
    short* Abf = (short*)d_ws;
    short* Btb = Abf + (size_t)MATN * MATN;
    convert_A_k<<<(MATN * (size_t)MATN) / 8 / 256, 256, 0, stream>>>(A, Abf);
    transpose_B_k<<<dim3(MATN / 64, MATN / 64), 256, 0, stream>>>(B, Btb);
    gemm_tril<<<4096, 256, 0, stream>>>(Abf, Btb, C);
  } else {
    gemm_tril_f32<<<dim3(MATN / 64, MATN / 64), 256, 0, stream>>>(A, B, C);
  }
}